// Round 1
// baseline (99.671 us; speedup 1.0000x reference)
//
#include <hip/hip_runtime.h>
#include <math.h>

#define NBOX 100
#define NBATCH 32
#define NCLS 80
#define PIX_PER_BATCH 5456  // 4096+1024+256+64+16

// ---------------- Kernel 1: per-batch stable descending-area sort -----------
__global__ __launch_bounds__(128) void fcos_sort_kernel(
    const float* __restrict__ boxes,   // [B,100,4]
    const int* __restrict__ labels,    // [B,100]
    const int* __restrict__ valid,     // [B,100]
    float4* __restrict__ sboxes,       // [B,100] sorted
    int* __restrict__ slab)            // [B,100] sorted labels, -1 = invalid
{
    int b = blockIdx.x;
    int tid = threadIdx.x;
    __shared__ float area_s[NBOX];
    __shared__ float4 box_s[NBOX];
    __shared__ int lab_s[NBOX];
    if (tid < NBOX) {
        float4 bx = ((const float4*)boxes)[b * NBOX + tid];
        int v = valid[b * NBOX + tid];
        float area = (bx.z - bx.x) * (bx.w - bx.y);
        area_s[tid] = (v != 0) ? area : -INFINITY;
        box_s[tid] = bx;
        lab_s[tid] = (v != 0) ? labels[b * NBOX + tid] : -1;
    }
    __syncthreads();
    if (tid < NBOX) {
        float my = area_s[tid];
        int rank = 0;
        #pragma unroll 4
        for (int j = 0; j < NBOX; ++j) {
            float aj = area_s[j];
            // stable descending: strictly larger area first; ties by index
            rank += ((aj > my) || (aj == my && j < tid)) ? 1 : 0;
        }
        sboxes[b * NBOX + rank] = box_s[tid];
        slab[b * NBOX + rank] = lab_s[tid];
    }
}

// ---------------- Kernel 2: encode all levels, 1 thread per pixel -----------
__global__ __launch_bounds__(256) void fcos_encode_kernel(
    const float4* __restrict__ sboxes, // [B,100]
    const int* __restrict__ slab,      // [B,100]
    float* __restrict__ out)
{
    __shared__ float4 sb[NBOX];
    __shared__ int sl[NBOX];
    int b = blockIdx.y;
    int tid = threadIdx.x;
    if (tid < NBOX) {
        sb[tid] = sboxes[b * NBOX + tid];
        sl[tid] = slab[b * NBOX + tid];
    }
    __syncthreads();

    int p = blockIdx.x * 256 + tid;
    if (p >= PIX_PER_BATCH) return;

    // decode level
    int base, lw;
    float s, rmin, rmax;
    int coff, ceoff, boff;
    if (p < 4096)       { base = 0;    lw = 6; s = 8.f;   rmin = 0.f;   rmax = 64.f;
                          coff = 0;        ceoff = 13967360; boff = 14141952; }
    else if (p < 5120)  { base = 4096; lw = 5; s = 16.f;  rmin = 64.f;  rmax = 128.f;
                          coff = 10485760; ceoff = 14098432; boff = 14666240; }
    else if (p < 5376)  { base = 5120; lw = 4; s = 32.f;  rmin = 128.f; rmax = 256.f;
                          coff = 13107200; ceoff = 14131200; boff = 14797312; }
    else if (p < 5440)  { base = 5376; lw = 3; s = 64.f;  rmin = 256.f; rmax = 512.f;
                          coff = 13762560; ceoff = 14139392; boff = 14830080; }
    else                { base = 5440; lw = 2; s = 128.f; rmin = 512.f; rmax = INFINITY;
                          coff = 13926400; ceoff = 14141440; boff = 14838272; }

    int rel = p - base;
    int W = 1 << lw;
    int A = W * W;
    int y = rel >> lw;
    int x = rel & (W - 1);

    float xF = (float)x, yF = (float)y;
    float cxp = (xF + 0.5f) * s;
    float cyp = (yF + 0.5f) * s;
    float inv_s = 1.0f / s;  // s is a power of two -> exact

    unsigned long long bits_lo = 0ull;
    unsigned int bits_hi = 0u;
    float cen = 0.f;
    float bl = 0.f, bt = 0.f, br = 0.f, bb = 0.f;

    for (int i = 0; i < NBOX; ++i) {
        int lab = sl[i];
        if (lab < 0) continue;  // invalid boxes (sorted to tail) never write
        float4 bx4 = sb[i];
        float xf = truncf(bx4.x * inv_s + 0.5f);
        float xl = truncf(bx4.z * inv_s - 0.5f);
        float yf = truncf(bx4.y * inv_s + 0.5f);
        float yl = truncf(bx4.w * inv_s - 0.5f);
        bool mask = (yF >= yf) & (yF <= yl) & (xF >= xf) & (xF <= xl);
        if (!mask) continue;

        float l_ = cxp - bx4.x;
        float t_ = cyp - bx4.y;
        float r_ = bx4.z - cxp;
        float b_ = bx4.w - cyp;
        float num = fminf(l_, r_) * fminf(t_, b_);
        float den = fmaxf(l_, r_) * fmaxf(t_, b_);
        cen = sqrtf(fmaxf(num / fmaxf(den, 1e-12f), 1e-12f));
        float mval = fmaxf(fmaxf(l_, t_), fmaxf(r_, b_));
        bool ok = (mval >= rmin) & (mval < rmax);

        if (lab < 64) {
            unsigned long long bit = 1ull << lab;
            bits_lo = ok ? (bits_lo | bit) : (bits_lo & ~bit);
        } else {
            unsigned int bit = 1u << (lab - 64);
            bits_hi = ok ? (bits_hi | bit) : (bits_hi & ~bit);
        }
        if (ok) { bl = l_; bt = t_; br = r_; bb = b_; }
    }

    // ---- write outputs (channel-first [B,C,H,W], levels concatenated) ----
    // cls: 80 channels
    {
        size_t o = (size_t)coff + (size_t)b * NCLS * A + rel;
        #pragma unroll 8
        for (int c = 0; c < 64; ++c) {
            out[o + (size_t)c * A] = ((bits_lo >> c) & 1ull) ? 1.0f : 0.0f;
        }
        #pragma unroll 8
        for (int c = 0; c < 16; ++c) {
            out[o + (size_t)(64 + c) * A] = ((bits_hi >> c) & 1u) ? 1.0f : 0.0f;
        }
    }
    // centerness: 1 channel
    out[(size_t)ceoff + (size_t)b * A + rel] = cen;
    // box: 4 channels (l,t,r,b)
    {
        size_t o = (size_t)boff + (size_t)b * 4 * A + rel;
        out[o] = bl;
        out[o + (size_t)A] = bt;
        out[o + (size_t)2 * A] = br;
        out[o + (size_t)3 * A] = bb;
    }
}

extern "C" void kernel_launch(void* const* d_in, const int* in_sizes, int n_in,
                              void* d_out, int out_size, void* d_ws, size_t ws_size,
                              hipStream_t stream) {
    const float* boxes = (const float*)d_in[0];   // [32,100,4] f32
    const int* labels = (const int*)d_in[1];      // [32,100] i32
    const int* valid = (const int*)d_in[2];       // [32,100] i32
    float* out = (float*)d_out;

    float4* sboxes = (float4*)d_ws;                       // 32*100*16 = 51200 B
    int* slab = (int*)((char*)d_ws + NBATCH * NBOX * sizeof(float4));

    fcos_sort_kernel<<<NBATCH, 128, 0, stream>>>(boxes, labels, valid, sboxes, slab);

    dim3 grid((PIX_PER_BATCH + 255) / 256, NBATCH);
    fcos_encode_kernel<<<grid, 256, 0, stream>>>(sboxes, slab, out);
}

// Round 3
// 98.447 us; speedup vs baseline: 1.0124x; 1.0124x over previous
//
#include <hip/hip_runtime.h>
#include <math.h>

#define NBOX 100
#define NBATCH 32
#define NCLS 80
#define PIX_PER_BATCH 5456  // 4096+1024+256+64+16

__device__ __forceinline__ void level_of(int p, int& base, int& lw, float& s,
                                         float& rmin, float& rmax,
                                         int& coff, int& ceoff, int& boff) {
    if (p < 4096)      { base=0;    lw=6; s=8.f;   rmin=0.f;   rmax=64.f;
                         coff=0;        ceoff=13967360; boff=14141952; }
    else if (p < 5120) { base=4096; lw=5; s=16.f;  rmin=64.f;  rmax=128.f;
                         coff=10485760; ceoff=14098432; boff=14666240; }
    else if (p < 5376) { base=5120; lw=4; s=32.f;  rmin=128.f; rmax=256.f;
                         coff=13107200; ceoff=14131200; boff=14797312; }
    else if (p < 5440) { base=5376; lw=3; s=64.f;  rmin=256.f; rmax=512.f;
                         coff=13762560; ceoff=14139392; boff=14830080; }
    else               { base=5440; lw=2; s=128.f; rmin=512.f; rmax=INFINITY;
                         coff=13926400; ceoff=14141440; boff=14838272; }
}

__global__ __launch_bounds__(256) void fcos_fused_kernel(
    const float4* __restrict__ boxes,  // [B,100]
    const int* __restrict__ labels,    // [B,100]
    const int* __restrict__ valid,     // [B,100]
    float* __restrict__ out)
{
    __shared__ float4 sbx[NBOX];      // sorted boxes
    __shared__ int    slb[NBOX];      // sorted labels (-1 = invalid, at tail)
    __shared__ float  sarea[NBOX];
    __shared__ float4 rawb[NBOX];
    __shared__ int    rawl[NBOX];
    __shared__ unsigned w0s[256], w1s[256], w2s[256];  // cls bitmask words
    __shared__ float scen[256], slf[256], stf[256], srf[256], sbf[256];

    int b = blockIdx.y;
    int tid = threadIdx.x;

    // ---- Phase A: block-local stable descending-area rank sort ----
    if (tid < NBOX) {
        float4 bx = boxes[b * NBOX + tid];
        int v = valid[b * NBOX + tid];
        rawb[tid] = bx;
        sarea[tid] = (v != 0) ? (bx.z - bx.x) * (bx.w - bx.y) : -INFINITY;
        rawl[tid] = (v != 0) ? labels[b * NBOX + tid] : -1;
    }
    __syncthreads();
    if (tid < NBOX) {
        float my = sarea[tid];
        int rank = 0;
        #pragma unroll 4
        for (int j = 0; j < NBOX; ++j) {
            float aj = sarea[j];
            rank += ((aj > my) || (aj == my && j < tid)) ? 1 : 0;
        }
        sbx[rank] = rawb[tid];
        slb[rank] = rawl[tid];
    }
    __syncthreads();

    // ---- Phase B: per-pixel folded scan ----
    int p = blockIdx.x * 256 + tid;
    unsigned long long bits_lo = 0ull;
    unsigned bits_hi = 0u;
    float cen = 0.f, bl = 0.f, bt = 0.f, br = 0.f, bb = 0.f;

    if (p < PIX_PER_BATCH) {
        int base, lw, coff, ceoff, boff; float s, rmin, rmax;
        level_of(p, base, lw, s, rmin, rmax, coff, ceoff, boff);
        int rel = p - base;
        int y = rel >> lw, x = rel & ((1 << lw) - 1);
        float xF = (float)x, yF = (float)y;
        float cxp = (xF + 0.5f) * s, cyp = (yF + 0.5f) * s;
        float inv_s = 1.0f / s;  // s power of two -> exact

        for (int i = 0; i < NBOX; ++i) {
            int lab = slb[i];
            if (lab < 0) break;   // invalid boxes sorted to tail
            float4 bx4 = sbx[i];
            float xf = truncf(bx4.x * inv_s + 0.5f);
            float xl = truncf(bx4.z * inv_s - 0.5f);
            float yf = truncf(bx4.y * inv_s + 0.5f);
            float yl = truncf(bx4.w * inv_s - 0.5f);
            bool mask = (yF >= yf) & (yF <= yl) & (xF >= xf) & (xF <= xl);
            if (!mask) continue;

            float l_ = cxp - bx4.x;
            float t_ = cyp - bx4.y;
            float r_ = bx4.z - cxp;
            float b_ = bx4.w - cyp;
            float num = fminf(l_, r_) * fminf(t_, b_);
            float den = fmaxf(l_, r_) * fmaxf(t_, b_);
            cen = sqrtf(fmaxf(num / fmaxf(den, 1e-12f), 1e-12f));
            float mval = fmaxf(fmaxf(l_, t_), fmaxf(r_, b_));
            bool ok = (mval >= rmin) & (mval < rmax);

            if (lab < 64) {
                unsigned long long bit = 1ull << lab;
                bits_lo = ok ? (bits_lo | bit) : (bits_lo & ~bit);
            } else {
                unsigned bit = 1u << (lab - 64);
                bits_hi = ok ? (bits_hi | bit) : (bits_hi & ~bit);
            }
            if (ok) { bl = l_; bt = t_; br = r_; bb = b_; }
        }
    }
    w0s[tid] = (unsigned)bits_lo;
    w1s[tid] = (unsigned)(bits_lo >> 32);
    w2s[tid] = bits_hi;
    scen[tid] = cen; slf[tid] = bl; stf[tid] = bt; srf[tid] = br; sbf[tid] = bb;
    __syncthreads();

    // ---- Phase C: cooperative float4 writes ----
    // wave wv owns a 20-channel slice (8 from word0, 8 from word1, 4 from word2);
    // lane owns pixel group g = 4 consecutive pixels (level-uniform per group).
    int lane = tid & 63, wv = tid >> 6;
    int g = lane;
    int gp = blockIdx.x * 256 + 4 * g;
    if (gp < PIX_PER_BATCH) {
        int base, lw, coff, ceoff, boff; float s, rmin, rmax;
        level_of(gp, base, lw, s, rmin, rmax, coff, ceoff, boff);
        int A = 1 << (2 * lw);
        int relg = gp - base;

        uint4 q0 = *(const uint4*)&w0s[4 * g];
        uint4 q1 = *(const uint4*)&w1s[4 * g];
        uint4 q2 = *(const uint4*)&w2s[4 * g];

        size_t obase = (size_t)coff + (size_t)b * NCLS * A + relg;

        #pragma unroll
        for (int cc = 0; cc < 8; ++cc) {      // word0: channels wv*8+cc
            int c = wv * 8 + cc;
            float4 v;
            v.x = ((q0.x >> c) & 1u) ? 1.f : 0.f;
            v.y = ((q0.y >> c) & 1u) ? 1.f : 0.f;
            v.z = ((q0.z >> c) & 1u) ? 1.f : 0.f;
            v.w = ((q0.w >> c) & 1u) ? 1.f : 0.f;
            *(float4*)&out[obase + (size_t)c * A] = v;
        }
        #pragma unroll
        for (int cc = 0; cc < 8; ++cc) {      // word1: channels 32+wv*8+cc
            int c = wv * 8 + cc;
            float4 v;
            v.x = ((q1.x >> c) & 1u) ? 1.f : 0.f;
            v.y = ((q1.y >> c) & 1u) ? 1.f : 0.f;
            v.z = ((q1.z >> c) & 1u) ? 1.f : 0.f;
            v.w = ((q1.w >> c) & 1u) ? 1.f : 0.f;
            *(float4*)&out[obase + (size_t)(32 + c) * A] = v;
        }
        #pragma unroll
        for (int cc = 0; cc < 4; ++cc) {      // word2: channels 64+wv*4+cc
            int c = wv * 4 + cc;
            float4 v;
            v.x = ((q2.x >> c) & 1u) ? 1.f : 0.f;
            v.y = ((q2.y >> c) & 1u) ? 1.f : 0.f;
            v.z = ((q2.z >> c) & 1u) ? 1.f : 0.f;
            v.w = ((q2.w >> c) & 1u) ? 1.f : 0.f;
            *(float4*)&out[obase + (size_t)(64 + c) * A] = v;
        }

        // box: wave wv writes box channel wv; wave 0 also writes centerness
        const float* barr = (wv == 0) ? slf : (wv == 1) ? stf : (wv == 2) ? srf : sbf;
        float4 bv = *(const float4*)&barr[4 * g];
        *(float4*)&out[(size_t)boff + (size_t)b * 4 * A + (size_t)wv * A + relg] = bv;
        if (wv == 0) {
            float4 cv = *(const float4*)&scen[4 * g];
            *(float4*)&out[(size_t)ceoff + (size_t)b * A + relg] = cv;
        }
    }
}

extern "C" void kernel_launch(void* const* d_in, const int* in_sizes, int n_in,
                              void* d_out, int out_size, void* d_ws, size_t ws_size,
                              hipStream_t stream) {
    const float4* boxes = (const float4*)d_in[0];  // [32,100,4] f32
    const int* labels = (const int*)d_in[1];       // [32,100] i32
    const int* valid = (const int*)d_in[2];        // [32,100] i32
    float* out = (float*)d_out;

    dim3 grid((PIX_PER_BATCH + 255) / 256, NBATCH);
    fcos_fused_kernel<<<grid, 256, 0, stream>>>(boxes, labels, valid, out);
}